// Round 6
// baseline (75.879 us; speedup 1.0000x reference)
//
#include <hip/hip_runtime.h>
#include <hip/hip_bf16.h>
#include <math.h>

// SpectralConv2d (FNO): B=16, Cin=Cout=32, H=W=256, MODES=16x16.
// Round-5 structure + depth-3 software prefetch in kF's main loop
// (issue-to-use gap ~816 cyc ~ HBM latency) and batched loads in kI stage 1.
//  kF (per b,i): T[m][w] = sum_h x[h][w] e^{-2pi i m h/256} (radix-2 over h),
//                P[m][p][w<128] = T[w] + (-1)^p T[w+128],
//                xsub[m][n] = sum_{w<128} P[m][n&1][w] e^{-2pi i n w/256}
//  kI (per b,o): os[m][n] = sum_i xsub*W; U[m][w0],U[m][w0+128] from one
//                os*tw product; y = (1/65536) Re(sum_m U e^{+2pi i m h/256})

#define PI_F 3.14159265358979323846f

__global__ __launch_bounds__(256, 2) void kF(const float* __restrict__ x,
                                             float2* __restrict__ xsub) {
    __shared__ float2 tw[256];
    __shared__ float2 Ts[16][4][65];     // [m][c][l], w = 4l+c, padded  33.3 KB
    __shared__ float2 redP[4128];        // union: red[4][4][4][64] / P[16][2][129]
    auto red = reinterpret_cast<float2 (*)[4][4][64]>(redP);
    auto P   = reinterpret_cast<float2 (*)[2][129]>(redP);

    const int t = threadIdx.x;
    { float ang = (2.0f * PI_F / 256.0f) * (float)t;
      tw[t] = make_float2(__cosf(ang), __sinf(ang)); }
    __syncthreads();

    const int bi = blockIdx.x;
    const float* xp = x + (size_t)bi * 65536;
    const int l = t & 63, wv = t >> 6;   // lane: w = 4l..4l+3; wave = h-chunk

    float Tr[4][16], Ti[4][16];
#pragma unroll
    for (int c = 0; c < 4; ++c)
#pragma unroll
        for (int m = 0; m < 16; ++m) { Tr[c][m] = 0.0f; Ti[c][m] = 0.0f; }

    const int h0 = wv * 32;
    const float4* xq = (const float4*)xp;    // index (h*64 + l)

    // depth-3 prefetch pipeline (all indices compile-time under unroll)
    float4 va[3], vb[3];
#pragma unroll
    for (int p = 0; p < 3; ++p) {
        va[p] = xq[(h0 + p) * 64 + l];
        vb[p] = xq[(h0 + p + 128) * 64 + l];
    }

#pragma unroll 4
    for (int j = 0; j < 32; ++j) {
        const int jp = (j + 3) & 31;         // wrap: last iters re-load h0..h0+2
        float4 na = xq[(h0 + jp) * 64 + l];
        float4 nb = xq[(h0 + jp + 128) * 64 + l];

        const int h = h0 + j;                // h-pair (h, h+128)
        const float4 v0 = va[0], v1 = vb[0];
        const float xe[4] = {v0.x + v1.x, v0.y + v1.y, v0.z + v1.z, v0.w + v1.w};
        const float xo[4] = {v0.x - v1.x, v0.y - v1.y, v0.z - v1.z, v0.w - v1.w};
#pragma unroll
        for (int m = 0; m < 16; ++m) {
            float2 cs = tw[(m * h) & 255];           // wave-uniform broadcast
#pragma unroll
            for (int c = 0; c < 4; ++c) {
                float xv = (m & 1) ? xo[c] : xe[c];
                Tr[c][m] = fmaf(xv, cs.x, Tr[c][m]); // e^{-ia} = (cos, -sin)
                Ti[c][m] = fmaf(-xv, cs.y, Ti[c][m]);
            }
        }
        va[0] = va[1]; vb[0] = vb[1];
        va[1] = va[2]; vb[1] = vb[2];
        va[2] = na;    vb[2] = nb;
    }

    // cross-wave reduce into Ts, 4 m-groups of 4
#pragma unroll
    for (int mg = 0; mg < 4; ++mg) {
        if (mg) __syncthreads();
#pragma unroll
        for (int mm = 0; mm < 4; ++mm)
#pragma unroll
            for (int c = 0; c < 4; ++c)
                red[wv][mm][c][l] = make_float2(Tr[c][mg * 4 + mm], Ti[c][mg * 4 + mm]);
        __syncthreads();
        const int mq = t >> 6, idx = t & 63;
#pragma unroll
        for (int c = 0; c < 4; ++c) {
            float2 a0 = red[0][mq][c][idx], a1 = red[1][mq][c][idx];
            float2 a2 = red[2][mq][c][idx], a3 = red[3][mq][c][idx];
            Ts[mg * 4 + mq][c][idx] =
                make_float2(a0.x + a1.x + a2.x + a3.x, a0.y + a1.y + a2.y + a3.y);
        }
    }
    __syncthreads();                      // red no longer live; P may overwrite

    // parity precombine: P[m][p][w] = T[m][w] + (-1)^p T[m][w+128], w<128
#pragma unroll
    for (int k = 0; k < 8; ++k) {
        const int s = k * 256 + t;        // 16m x 128w slots
        const int m = s >> 7, w = s & 127;
        const int c = w & 3, li = w >> 2; // w = 4*li + c; w+128 -> li+32
        float2 A = Ts[m][c][li], Bv = Ts[m][c][li + 32];
        P[m][0][w] = make_float2(A.x + Bv.x, A.y + Bv.y);
        P[m][1][w] = make_float2(A.x - Bv.x, A.y - Bv.y);
    }
    __syncthreads();

    // w-DFT tail: thread (m = t>>4, n = t&15), 128 iters on parity plane
    const int m = t >> 4, n = t & 15;
    const float2* Pp = &P[m][n & 1][0];
    float ang = (2.0f * PI_F / 256.0f) * (float)n;
    float c1 = __cosf(ang), s1 = __sinf(ang);
    float cr = 1.0f, ci = 0.0f;
    float ar = 0.0f, ai = 0.0f;
    for (int w = 0; w < 128; ++w) {
        float2 Tv = Pp[w];               // 8 distinct banks/wave, broadcast
        ar += Tv.x * cr + Tv.y * ci;     // * e^{-i n w}
        ai += Tv.y * cr - Tv.x * ci;
        float nr = fmaf(cr, c1, -ci * s1);
        float nc = fmaf(cr, s1, ci * c1);
        cr = nr; ci = nc;
    }
    xsub[(size_t)bi * 256 + t] = make_float2(ar, ai);
}

__global__ __launch_bounds__(256, 2) void kI(const float2* __restrict__ xsub,
                                             const float* __restrict__ wr,
                                             const float* __restrict__ wi,
                                             float* __restrict__ y) {
    __shared__ float2 tw[256];
    __shared__ float2 os[256];
    __shared__ float2 U[16][256];        // 32 KB
    const int t = threadIdx.x;
    { float ang = (2.0f * PI_F / 256.0f) * (float)t;
      tw[t] = make_float2(__cosf(ang), __sinf(ang)); }

    const int bo = blockIdx.x, b = bo >> 5, o = bo & 31;

    // stage 1: channel mix over Cin (unroll 8 -> batched loads in flight)
    {
        float ar = 0.0f, ai = 0.0f;
#pragma unroll 8
        for (int i = 0; i < 32; ++i) {
            float2 xv = xsub[(size_t)(b * 32 + i) * 256 + t];
            float wre = wr[(size_t)(i * 32 + o) * 256 + t];
            float wim = wi[(size_t)(i * 32 + o) * 256 + t];
            ar += xv.x * wre - xv.y * wim;
            ai += xv.x * wim + xv.y * wre;
        }
        os[t] = make_float2(ar, ai);
    }
    __syncthreads();

    // stage 2: radix-2 over w: thread (mh = t>>7, w0 = t&127) fills
    // U[m][w0] and U[m][w0+128] from one os*tw product ((-1)^n sign)
    {
        const int w0 = t & 127, mh = t >> 7;
        float twr[16], twi[16];
#pragma unroll
        for (int n = 0; n < 16; ++n) {
            float2 cs = tw[(n * w0) & 255];
            twr[n] = cs.x; twi[n] = cs.y;
        }
#pragma unroll
        for (int mm = 0; mm < 8; ++mm) {
            const int m = mh * 8 + mm;
            float u0r = 0.f, u0i = 0.f, u1r = 0.f, u1i = 0.f;
#pragma unroll
            for (int n = 0; n < 16; ++n) {
                float2 ov = os[m * 16 + n];          // uniform -> broadcast
                float tr = ov.x * twr[n] - ov.y * twi[n];   // * e^{+i n w0}
                float ti2 = ov.x * twi[n] + ov.y * twr[n];
                u0r += tr; u0i += ti2;
                if (n & 1) { u1r -= tr; u1i -= ti2; }
                else       { u1r += tr; u1i += ti2; }
            }
            U[m][w0]       = make_float2(u0r, u0i);
            U[m][w0 + 128] = make_float2(u1r, u1i);
        }
    }
    __syncthreads();

    // stage 3: inverse h-DFT (radix-2 over h), lane owns w = 4l..4l+3
    const int l = t & 63, wv = t >> 6;
    float Ur[4][16], Ui[4][16];
#pragma unroll
    for (int m = 0; m < 16; ++m) {
        const float4* Um = (const float4*)&U[m][0];
        float4 p0 = Um[2 * l], p1 = Um[2 * l + 1];
        Ur[0][m] = p0.x; Ui[0][m] = p0.y; Ur[1][m] = p0.z; Ui[1][m] = p0.w;
        Ur[2][m] = p1.x; Ui[2][m] = p1.y; Ur[3][m] = p1.z; Ui[3][m] = p1.w;
    }

    float* yp = y + (size_t)bo * 65536;
    const float inv = 1.0f / 65536.0f;
#pragma unroll 2
    for (int j = 0; j < 32; ++j) {
        const int h = wv * 32 + j;       // h-pair (h, h+128)
        float ae[4] = {0, 0, 0, 0}, ao[4] = {0, 0, 0, 0};
#pragma unroll
        for (int m = 0; m < 16; ++m) {
            float2 cs = tw[(m * h) & 255];           // uniform -> broadcast
#pragma unroll
            for (int c = 0; c < 4; ++c) {
                float v = fmaf(Ur[c][m], cs.x, -Ui[c][m] * cs.y); // Re(U e^{+ia})
                if (m & 1) ao[c] += v; else ae[c] += v;
            }
        }
        float4 ye, yo2;
        ye.x = (ae[0] + ao[0]) * inv; ye.y = (ae[1] + ao[1]) * inv;
        ye.z = (ae[2] + ao[2]) * inv; ye.w = (ae[3] + ao[3]) * inv;
        yo2.x = (ae[0] - ao[0]) * inv; yo2.y = (ae[1] - ao[1]) * inv;
        yo2.z = (ae[2] - ao[2]) * inv; yo2.w = (ae[3] - ao[3]) * inv;
        ((float4*)(yp + h * 256))[l] = ye;
        ((float4*)(yp + (h + 128) * 256))[l] = yo2;
    }
}

extern "C" void kernel_launch(void* const* d_in, const int* in_sizes, int n_in,
                              void* d_out, int out_size, void* d_ws, size_t ws_size,
                              hipStream_t stream) {
    const float* x  = (const float*)d_in[0];   // [16][32][256][256]
    const float* wr = (const float*)d_in[1];   // [32][32][16][16]
    const float* wi = (const float*)d_in[2];   // [32][32][16][16]
    float* y = (float*)d_out;                  // [16][32][256][256]

    float2* xsub = (float2*)d_ws;              // 512*256*8 = 1 MB

    kF<<<512, 256, 0, stream>>>(x, xsub);
    kI<<<512, 256, 0, stream>>>(xsub, wr, wi, y);
}

// Round 8
// 73.302 us; speedup vs baseline: 1.0351x; 1.0351x over previous
//
#include <hip/hip_runtime.h>
#include <hip/hip_bf16.h>
#include <math.h>

// SpectralConv2d (FNO): B=16, Cin=Cout=32, H=W=256, MODES=16x16.
// Round-5 structure; main loops use per-m in-register complex rotators
// (wave-uniform VGPR values) instead of per-iteration LDS twiddle broadcasts.
//  kF (per b,i): T[m][w] = sum_h x[h][w] e^{-2pi i m h/256} (radix-2 over h),
//                P[m][p][w<128] = T[w] + (-1)^p T[w+128],
//                xsub[m][n] = sum_{w<128} P[m][n&1][w] e^{-2pi i n w/256}
//  kI (per b,o): os[m][n] = sum_i xsub*W; U[m][w0],U[m][w0+128] from one
//                os*tw product; y = (1/65536) Re(sum_m U e^{+2pi i m h/256})

#define PI_F 3.14159265358979323846f

__global__ __launch_bounds__(256, 2) void kF(const float* __restrict__ x,
                                             float2* __restrict__ xsub) {
    __shared__ float2 tw[256];
    __shared__ float2 Ts[16][4][65];     // [m][c][l], w = 4l+c, padded  33.3 KB
    __shared__ float2 redP[4128];        // union: red[4][4][4][64] / P[16][2][129]
    auto red = reinterpret_cast<float2 (*)[4][4][64]>(redP);
    auto P   = reinterpret_cast<float2 (*)[2][129]>(redP);

    const int t = threadIdx.x;
    { float ang = (2.0f * PI_F / 256.0f) * (float)t;
      tw[t] = make_float2(__cosf(ang), __sinf(ang)); }
    __syncthreads();

    const int bi = blockIdx.x;
    const float* xp = x + (size_t)bi * 65536;
    const int l = t & 63, wv = t >> 6;   // lane: w = 4l..4l+3; wave = h-chunk
    const int h0 = wv * 32;

    float Tr[4][16], Ti[4][16];
#pragma unroll
    for (int c = 0; c < 4; ++c)
#pragma unroll
        for (int m = 0; m < 16; ++m) { Tr[c][m] = 0.0f; Ti[c][m] = 0.0f; }

    // per-m rotators R_m = e^{-2pi i m h/256} (wave-uniform values in VGPRs)
    float Rr[16], Ri[16], Sr[16], Si[16];
#pragma unroll
    for (int m = 0; m < 16; ++m) {
        float2 i0 = tw[(m * h0) & 255];
        Rr[m] = i0.x; Ri[m] = -i0.y;     // e^{-i m h0}
        float2 st = tw[m];
        Sr[m] = st.x;                    // e^{-i m} = (cos, -sin)
        Si[m] = -st.y;
    }

#pragma unroll 2
    for (int j = 0; j < 32; ++j) {
        const int h = h0 + j;            // h-pair (h, h+128)
        const float4 v0 = ((const float4*)(xp + h * 256))[l];
        const float4 v1 = ((const float4*)(xp + (h + 128) * 256))[l];
        const float xe[4] = {v0.x + v1.x, v0.y + v1.y, v0.z + v1.z, v0.w + v1.w};
        const float xo[4] = {v0.x - v1.x, v0.y - v1.y, v0.z - v1.z, v0.w - v1.w};
#pragma unroll
        for (int m = 0; m < 16; ++m) {
            const float cr = Rr[m], ci = Ri[m];
#pragma unroll
            for (int c = 0; c < 4; ++c) {
                float xv = (m & 1) ? xo[c] : xe[c];
                Tr[c][m] = fmaf(xv, cr, Tr[c][m]);
                Ti[c][m] = fmaf(xv, ci, Ti[c][m]);
            }
            Rr[m] = fmaf(cr, Sr[m], -ci * Si[m]);     // R *= S
            Ri[m] = fmaf(cr, Si[m],  ci * Sr[m]);
        }
    }

    // cross-wave reduce into Ts, 4 m-groups of 4
#pragma unroll
    for (int mg = 0; mg < 4; ++mg) {
        if (mg) __syncthreads();
#pragma unroll
        for (int mm = 0; mm < 4; ++mm)
#pragma unroll
            for (int c = 0; c < 4; ++c)
                red[wv][mm][c][l] = make_float2(Tr[c][mg * 4 + mm], Ti[c][mg * 4 + mm]);
        __syncthreads();
        const int mq = t >> 6, idx = t & 63;
#pragma unroll
        for (int c = 0; c < 4; ++c) {
            float2 a0 = red[0][mq][c][idx], a1 = red[1][mq][c][idx];
            float2 a2 = red[2][mq][c][idx], a3 = red[3][mq][c][idx];
            Ts[mg * 4 + mq][c][idx] =
                make_float2(a0.x + a1.x + a2.x + a3.x, a0.y + a1.y + a2.y + a3.y);
        }
    }
    __syncthreads();                      // red no longer live; P may overwrite

    // parity precombine: P[m][p][w] = T[m][w] + (-1)^p T[m][w+128], w<128
#pragma unroll
    for (int k = 0; k < 8; ++k) {
        const int s = k * 256 + t;        // 16m x 128w slots
        const int m = s >> 7, w = s & 127;
        const int c = w & 3, li = w >> 2; // w = 4*li + c; w+128 -> li+32
        float2 A = Ts[m][c][li], Bv = Ts[m][c][li + 32];
        P[m][0][w] = make_float2(A.x + Bv.x, A.y + Bv.y);
        P[m][1][w] = make_float2(A.x - Bv.x, A.y - Bv.y);
    }
    __syncthreads();

    // w-DFT tail: thread (m = t>>4, n = t&15), 128 iters on parity plane
    const int m = t >> 4, n = t & 15;
    const float2* Pp = &P[m][n & 1][0];
    float ang = (2.0f * PI_F / 256.0f) * (float)n;
    float c1 = __cosf(ang), s1 = __sinf(ang);
    float cr = 1.0f, ci = 0.0f;
    float ar = 0.0f, ai = 0.0f;
    for (int w = 0; w < 128; ++w) {
        float2 Tv = Pp[w];               // 8 distinct banks/wave, broadcast
        ar += Tv.x * cr + Tv.y * ci;     // * e^{-i n w}
        ai += Tv.y * cr - Tv.x * ci;
        float nr = fmaf(cr, c1, -ci * s1);
        float nc = fmaf(cr, s1, ci * c1);
        cr = nr; ci = nc;
    }
    xsub[(size_t)bi * 256 + t] = make_float2(ar, ai);
}

__global__ __launch_bounds__(256, 2) void kI(const float2* __restrict__ xsub,
                                             const float* __restrict__ wr,
                                             const float* __restrict__ wi,
                                             float* __restrict__ y) {
    __shared__ float2 tw[256];
    __shared__ float2 os[256];
    __shared__ float2 U[16][256];        // 32 KB
    const int t = threadIdx.x;
    { float ang = (2.0f * PI_F / 256.0f) * (float)t;
      tw[t] = make_float2(__cosf(ang), __sinf(ang)); }

    const int bo = blockIdx.x, b = bo >> 5, o = bo & 31;

    // stage 1: channel mix over Cin (unroll 8 -> batched loads in flight)
    {
        float ar = 0.0f, ai = 0.0f;
#pragma unroll 8
        for (int i = 0; i < 32; ++i) {
            float2 xv = xsub[(size_t)(b * 32 + i) * 256 + t];
            float wre = wr[(size_t)(i * 32 + o) * 256 + t];
            float wim = wi[(size_t)(i * 32 + o) * 256 + t];
            ar += xv.x * wre - xv.y * wim;
            ai += xv.x * wim + xv.y * wre;
        }
        os[t] = make_float2(ar, ai);
    }
    __syncthreads();

    // stage 2: radix-2 over w: thread (mh = t>>7, w0 = t&127) fills
    // U[m][w0] and U[m][w0+128] from one os*tw product ((-1)^n sign)
    {
        const int w0 = t & 127, mh = t >> 7;
        float twr[16], twi[16];
#pragma unroll
        for (int n = 0; n < 16; ++n) {
            float2 cs = tw[(n * w0) & 255];
            twr[n] = cs.x; twi[n] = cs.y;
        }
#pragma unroll
        for (int mm = 0; mm < 8; ++mm) {
            const int m = mh * 8 + mm;
            float u0r = 0.f, u0i = 0.f, u1r = 0.f, u1i = 0.f;
#pragma unroll
            for (int n = 0; n < 16; ++n) {
                float2 ov = os[m * 16 + n];          // uniform -> broadcast
                float tr = ov.x * twr[n] - ov.y * twi[n];   // * e^{+i n w0}
                float ti2 = ov.x * twi[n] + ov.y * twr[n];
                u0r += tr; u0i += ti2;
                if (n & 1) { u1r -= tr; u1i -= ti2; }
                else       { u1r += tr; u1i += ti2; }
            }
            U[m][w0]       = make_float2(u0r, u0i);
            U[m][w0 + 128] = make_float2(u1r, u1i);
        }
    }
    __syncthreads();

    // stage 3: inverse h-DFT (radix-2 over h), lane owns w = 4l..4l+3;
    // twiddles via per-m rotators (wave-uniform), no LDS in the loop
    const int l = t & 63, wv = t >> 6;
    const int h0 = wv * 32;
    float Ur[4][16], Ui[4][16];
#pragma unroll
    for (int m = 0; m < 16; ++m) {
        const float4* Um = (const float4*)&U[m][0];
        float4 p0 = Um[2 * l], p1 = Um[2 * l + 1];
        Ur[0][m] = p0.x; Ui[0][m] = p0.y; Ur[1][m] = p0.z; Ui[1][m] = p0.w;
        Ur[2][m] = p1.x; Ui[2][m] = p1.y; Ur[3][m] = p1.z; Ui[3][m] = p1.w;
    }
    float Rr[16], Ri[16], Sr[16], Si[16];
#pragma unroll
    for (int m = 0; m < 16; ++m) {
        float2 i0 = tw[(m * h0) & 255];
        Rr[m] = i0.x; Ri[m] = i0.y;      // e^{+i m h0}
        float2 st = tw[m];
        Sr[m] = st.x;                    // e^{+i m}
        Si[m] = st.y;
    }

    float* yp = y + (size_t)bo * 65536;
    const float inv = 1.0f / 65536.0f;
#pragma unroll 2
    for (int j = 0; j < 32; ++j) {
        const int h = h0 + j;            // h-pair (h, h+128)
        float ae[4] = {0, 0, 0, 0}, ao[4] = {0, 0, 0, 0};
#pragma unroll
        for (int m = 0; m < 16; ++m) {
            const float cr = Rr[m], ci = Ri[m];
#pragma unroll
            for (int c = 0; c < 4; ++c) {
                float v = fmaf(Ur[c][m], cr, -(Ui[c][m] * ci)); // Re(U e^{+ia})
                if (m & 1) ao[c] += v; else ae[c] += v;
            }
            Rr[m] = fmaf(cr, Sr[m], -ci * Si[m]);     // R *= S
            Ri[m] = fmaf(cr, Si[m],  ci * Sr[m]);
        }
        float4 ye, yo2;
        ye.x = (ae[0] + ao[0]) * inv; ye.y = (ae[1] + ao[1]) * inv;
        ye.z = (ae[2] + ao[2]) * inv; ye.w = (ae[3] + ao[3]) * inv;
        yo2.x = (ae[0] - ao[0]) * inv; yo2.y = (ae[1] - ao[1]) * inv;
        yo2.z = (ae[2] - ao[2]) * inv; yo2.w = (ae[3] - ao[3]) * inv;
        ((float4*)(yp + h * 256))[l] = ye;
        ((float4*)(yp + (h + 128) * 256))[l] = yo2;
    }
}

extern "C" void kernel_launch(void* const* d_in, const int* in_sizes, int n_in,
                              void* d_out, int out_size, void* d_ws, size_t ws_size,
                              hipStream_t stream) {
    const float* x  = (const float*)d_in[0];   // [16][32][256][256]
    const float* wr = (const float*)d_in[1];   // [32][32][16][16]
    const float* wi = (const float*)d_in[2];   // [32][32][16][16]
    float* y = (float*)d_out;                  // [16][32][256][256]

    float2* xsub = (float2*)d_ws;              // 512*256*8 = 1 MB

    kF<<<512, 256, 0, stream>>>(x, xsub);
    kI<<<512, 256, 0, stream>>>(xsub, wr, wi, y);
}